// Round 1
// baseline (6018.769 us; speedup 1.0000x reference)
//
#include <hip/hip_runtime.h>
#include <hip/hip_fp16.h>

#define THREADS 128
#define B_ROWS  262144

// Per-thread-private activation rows live in LDS (dynamic indexing needs memory;
// registers can't be runtime-indexed without spilling to scratch).
// Strides chosen so bank = f(tid) spreads across all 32 banks (2-way max = free).
struct Smem {
  __half cur[THREADS][130];  // logical h (128) via indirection table P
  __half t1 [THREADS][66];   // MLP hidden 1 (64)
  __half t2 [THREADS][34];   // MLP hidden 2 (32)
  int    P  [2][128];        // composed permutation, double-buffered (shared, uniform)
};

// atan via odd minimax poly on [0,1] + reciprocal range reduction; |err| ~2e-6.
__device__ __forceinline__ float atan_f(float x) {
  float ax  = fabsf(x);
  bool  big = ax > 1.0f;
  float z   = big ? (1.0f / ax) : ax;
  float s   = z * z;
  float p   = -0.01172120f;
  p = fmaf(p, s,  0.05265332f);
  p = fmaf(p, s, -0.11643287f);
  p = fmaf(p, s,  0.19354346f);
  p = fmaf(p, s, -0.33262347f);
  p = fmaf(p, s,  0.99997726f);
  p = p * z;
  float r = big ? (1.57079632679f - p) : p;
  return (x < 0.0f) ? -r : r;
}

// One 3-layer MLP: logical input cols [inOff, inOff+64) of cur (via P), result -> out[64] (f32 regs).
// Weight indices are wave-uniform -> compiler should emit s_load + v_fmac(v,s,v).
__device__ __forceinline__ void mlp3(
    Smem& sm, int tid, const int* Pt, int inOff, int widx,
    const float* __restrict__ W1, const float* __restrict__ b1,
    const float* __restrict__ W2, const float* __restrict__ b2,
    const float* __restrict__ W3, const float* __restrict__ b3,
    float out[64])
{
  const float* w1 = W1 + widx * 64 * 64;
  const float* w2 = W2 + widx * 64 * 32;
  const float* w3 = W3 + widx * 32 * 64;
  const float* c1 = b1 + widx * 64;
  const float* c2 = b2 + widx * 32;
  const float* c3 = b3 + widx * 64;

  // layer 1: 64 -> 64
  float a[64];
  #pragma unroll
  for (int n = 0; n < 64; ++n) a[n] = c1[n];
  for (int k = 0; k < 64; ++k) {
    float hk = __half2float(sm.cur[tid][Pt[inOff + k]]);
    const float* wr = w1 + k * 64;
    #pragma unroll
    for (int n = 0; n < 64; ++n) a[n] = fmaf(hk, wr[n], a[n]);
  }
  #pragma unroll
  for (int n = 0; n < 64; ++n) sm.t1[tid][n] = __float2half(fmaxf(a[n], 0.0f));

  // layer 2: 64 -> 32
  float a2[32];
  #pragma unroll
  for (int n = 0; n < 32; ++n) a2[n] = c2[n];
  for (int k = 0; k < 64; ++k) {
    float hk = __half2float(sm.t1[tid][k]);
    const float* wr = w2 + k * 32;
    #pragma unroll
    for (int n = 0; n < 32; ++n) a2[n] = fmaf(hk, wr[n], a2[n]);
  }
  #pragma unroll
  for (int n = 0; n < 32; ++n) sm.t2[tid][n] = __float2half(fmaxf(a2[n], 0.0f));

  // layer 3: 32 -> 64
  #pragma unroll
  for (int n = 0; n < 64; ++n) out[n] = c3[n];
  for (int k = 0; k < 32; ++k) {
    float hk = __half2float(sm.t2[tid][k]);
    const float* wr = w3 + k * 64;
    #pragma unroll
    for (int n = 0; n < 64; ++n) out[n] = fmaf(hk, wr[n], out[n]);
  }
}

// One coupling half-step: y_out = exp(1.272*atan(MLP_s(in))) * x_out + MLP_t(in), in-place at outOff.
__device__ __forceinline__ void halfstep(
    Smem& sm, int tid, const int* Pt, int inOff, int outOff, int wS, int wT,
    const float* __restrict__ W1, const float* __restrict__ b1,
    const float* __restrict__ W2, const float* __restrict__ b2,
    const float* __restrict__ W3, const float* __restrict__ b3)
{
  float sa[64];
  mlp3(sm, tid, Pt, inOff, wS, W1, b1, W2, b2, W3, b3, sa);
  #pragma unroll
  for (int n = 0; n < 64; ++n) {
    float m  = __expf(1.272f * atan_f(sa[n]));
    int  ph  = Pt[outOff + n];
    float xv = __half2float(sm.cur[tid][ph]);
    sm.cur[tid][ph] = __float2half(m * xv);   // partial: exp(s)*x
  }
  float ta[64];
  mlp3(sm, tid, Pt, inOff, wT, W1, b1, W2, b2, W3, b3, ta);
  #pragma unroll
  for (int n = 0; n < 64; ++n) {
    int  ph = Pt[outOff + n];
    float v = __half2float(sm.cur[tid][ph]) + ta[n];
    sm.cur[tid][ph] = __float2half(v);        // final: exp(s)*x + t
  }
}

__global__ __launch_bounds__(THREADS) void fused_flow(
    const float* __restrict__ x,  const float* __restrict__ pad,
    const float* __restrict__ W1, const float* __restrict__ b1,
    const float* __restrict__ W2, const float* __restrict__ b2,
    const float* __restrict__ W3, const float* __restrict__ b3,
    const int*  __restrict__ perms, float* __restrict__ out)
{
  __shared__ Smem sm;
  const int tid = threadIdx.x;
  const size_t row = (size_t)blockIdx.x * THREADS + tid;

  // identity indirection
  sm.P[0][tid] = tid;

  // load h0 = [x, 0.01*pad] as fp16
  const float4* x4 = (const float4*)(x + row * 64);
  #pragma unroll
  for (int c4 = 0; c4 < 16; ++c4) {
    float4 v = x4[c4];
    sm.cur[tid][c4 * 4 + 0] = __float2half(v.x);
    sm.cur[tid][c4 * 4 + 1] = __float2half(v.y);
    sm.cur[tid][c4 * 4 + 2] = __float2half(v.z);
    sm.cur[tid][c4 * 4 + 3] = __float2half(v.w);
  }
  const float4* p4 = (const float4*)(pad + row * 64);
  #pragma unroll
  for (int c4 = 0; c4 < 16; ++c4) {
    float4 v = p4[c4];
    sm.cur[tid][64 + c4 * 4 + 0] = __float2half(0.01f * v.x);
    sm.cur[tid][64 + c4 * 4 + 1] = __float2half(0.01f * v.y);
    sm.cur[tid][64 + c4 * 4 + 2] = __float2half(0.01f * v.z);
    sm.cur[tid][64 + c4 * 4 + 3] = __float2half(0.01f * v.w);
  }
  __syncthreads();

  int pc = 0;
  for (int blk = 0; blk < 5; ++blk) {
    const int* Pt = sm.P[pc];
    // half-step 1: s2/t2 from x2 (logical [64,128)), update x1 slot -> y1
    halfstep(sm, tid, Pt, 64, 0, blk * 4 + 2, blk * 4 + 3, W1, b1, W2, b2, W3, b3);
    // half-step 2: s1/t1 from y1 (logical [0,64)), update x2 slot -> y2
    halfstep(sm, tid, Pt, 0, 64, blk * 4 + 0, blk * 4 + 1, W1, b1, W2, b2, W3, b3);
    // compose permutation: new logical c = old logical perm[c]
    __syncthreads();
    sm.P[pc ^ 1][tid] = Pt[perms[blk * 128 + tid]];
    __syncthreads();
    pc ^= 1;
  }

  // write out (fp32), applying the composed permutation
  const int* Pt = sm.P[pc];
  float4* o4 = (float4*)(out + row * 128);
  #pragma unroll
  for (int c4 = 0; c4 < 32; ++c4) {
    float4 v;
    v.x = __half2float(sm.cur[tid][Pt[c4 * 4 + 0]]);
    v.y = __half2float(sm.cur[tid][Pt[c4 * 4 + 1]]);
    v.z = __half2float(sm.cur[tid][Pt[c4 * 4 + 2]]);
    v.w = __half2float(sm.cur[tid][Pt[c4 * 4 + 3]]);
    o4[c4] = v;
  }
}

extern "C" void kernel_launch(void* const* d_in, const int* in_sizes, int n_in,
                              void* d_out, int out_size, void* d_ws, size_t ws_size,
                              hipStream_t stream) {
  const float* x    = (const float*)d_in[0];
  const float* pad  = (const float*)d_in[1];
  const float* W1   = (const float*)d_in[2];
  const float* b1   = (const float*)d_in[3];
  const float* W2   = (const float*)d_in[4];
  const float* b2   = (const float*)d_in[5];
  const float* W3   = (const float*)d_in[6];
  const float* b3   = (const float*)d_in[7];
  const int*   perms= (const int*)d_in[8];
  float* out = (float*)d_out;

  dim3 grid(B_ROWS / THREADS);
  dim3 block(THREADS);
  fused_flow<<<grid, block, 0, stream>>>(x, pad, W1, b1, W2, b2, W3, b3, perms, out);
}

// Round 2
// 851.401 us; speedup vs baseline: 7.0693x; 7.0693x over previous
//
#include <hip/hip_runtime.h>
#include <hip/hip_fp16.h>

typedef _Float16 f16x8 __attribute__((ext_vector_type(8)));
typedef _Float16 f16x4 __attribute__((ext_vector_type(4)));
typedef float    f32x4 __attribute__((ext_vector_type(4)));

#define B_ROWS    262144
#define WG_ROWS   128
#define WAVE_ROWS 32
#define THREADS   256
#define NBLK      5

// LDS byte layout (per WG). All rows XOR-swizzled in 16B slots to kill bank conflicts.
#define H_OFF   0        // h:    128 rows x 256B (128 f16), swz ^((row&7)<<4)
#define H1_OFF  32768    // hid1: 128 rows x 128B ( 64 f16), swz ^((row&7)<<4)
#define H2_OFF  49152    // hid2: 128 rows x  64B ( 32 f16), swz ^((row&3)<<4)
#define SMEM_BYTES 57344

#define LO_SCALE 256.0f
#define LO_INV   0.00390625f

// ---------------- weight packing: MFMA B-fragments, hi/lo fp16 split ----------------
// Per MLP (20 total): 32 frags x 64 lanes x 8 f16.  frag layout:
//   L1 (K=64,N=64): frag = (nt*2+ks)*2 + hl            (nt 0..3, ks 0..1)
//   L2 (K=64,N=32): frag = 16 + (nt*2+ks)*2 + hl       (nt 0..1)
//   L3 (K=32,N=64): frag = 24 + nt*2 + hl              (nt 0..3)
// B-frag lane map (16x16x32): lane l holds B[k = ks*32 + (l>>4)*8 + j][n = nt*16 + (l&15)]
__global__ __launch_bounds__(256) void pack_weights(
    const float* __restrict__ W1, const float* __restrict__ W2,
    const float* __restrict__ W3, __half* __restrict__ wp)
{
  int idx = blockIdx.x * 256 + threadIdx.x;        // 20 mlps * 16 fragpairs * 64 lanes
  if (idx >= 20480) return;
  int mlp  = idx >> 10;
  int rem  = idx & 1023;
  int s    = rem >> 6;          // fragpair 0..15
  int lane = rem & 63;
  int kg = lane >> 4, nl = lane & 15;

  int fh, k0, n, stride; const float* src;
  if (s < 8) {                  // L1
    fh = s * 2;
    k0 = (s & 1) * 32 + kg * 8;
    n  = (s >> 1) * 16 + nl;
    src = W1 + (size_t)mlp * 64 * 64; stride = 64;
  } else if (s < 12) {          // L2
    int s2 = s - 8; fh = 16 + s2 * 2;
    k0 = (s2 & 1) * 32 + kg * 8;
    n  = (s2 >> 1) * 16 + nl;
    src = W2 + (size_t)mlp * 64 * 32; stride = 32;
  } else {                      // L3
    int s3 = s - 12; fh = 24 + s3 * 2;
    k0 = kg * 8;
    n  = s3 * 16 + nl;
    src = W3 + (size_t)mlp * 32 * 64; stride = 64;
  }
  __half* dh = wp + (size_t)mlp * 16384 + (size_t)fh * 512 + lane * 8;
  __half* dl = dh + 512;
  #pragma unroll
  for (int j = 0; j < 8; ++j) {
    float w   = src[(size_t)(k0 + j) * stride + n];
    __half hi = __float2half(w);
    float  r  = (w - __half2float(hi)) * LO_SCALE;   // scaled residual stays in fp16-normal range
    dh[j] = hi;
    dl[j] = __float2half(r);
  }
}

// ---------------- math helpers ----------------
__device__ __forceinline__ float atan_f(float x) {
  float ax  = fabsf(x);
  bool  big = ax > 1.0f;
  float z   = big ? (1.0f / ax) : ax;
  float s   = z * z;
  float p   = -0.01172120f;
  p = fmaf(p, s,  0.05265332f);
  p = fmaf(p, s, -0.11643287f);
  p = fmaf(p, s,  0.19354346f);
  p = fmaf(p, s, -0.33262347f);
  p = fmaf(p, s,  0.99997726f);
  p = p * z;
  float r = big ? (1.57079632679f - p) : p;
  return (x < 0.0f) ? -r : r;
}

// ---------------- one 3-layer MLP on this wave's 32 rows ----------------
// input: h cols at byte offset inByteOff (0 -> cols 0..63, 128 -> cols 64..127)
// output: f32 accs oh/ol (combine as oh + ol*LO_INV), C/D map: col=l&15, row=(l>>4)*4+reg
__device__ __forceinline__ void run_mlp(
    char* sm, int r0, int lane, int inByteOff,
    const __half* __restrict__ wpm,
    const float* __restrict__ b1m, const float* __restrict__ b2m, const float* __restrict__ b3m,
    f32x4 oh[2][4], f32x4 ol[2][4])
{
  const int nl = lane & 15, kg = lane >> 4;
  const f16x8* wf = (const f16x8*)wpm;

  // -------- L1: K=64, N=64 --------
  f16x8 a1[2][2];
  #pragma unroll
  for (int mf = 0; mf < 2; ++mf) {
    const int row = r0 + mf * 16 + nl;
    const int swz = (row & 7) << 4;
    #pragma unroll
    for (int ks = 0; ks < 2; ++ks)
      a1[mf][ks] = *(const f16x8*)(sm + H_OFF + row * 256 + ((inByteOff + ks * 64 + kg * 16) ^ swz));
  }
  f32x4 ah[2][4], al[2][4];
  #pragma unroll
  for (int nt = 0; nt < 4; ++nt) {
    const float bb = b1m[nt * 16 + nl];
    #pragma unroll
    for (int mf = 0; mf < 2; ++mf) {
      ah[mf][nt] = f32x4{bb, bb, bb, bb};
      al[mf][nt] = f32x4{0.f, 0.f, 0.f, 0.f};
    }
  }
  #pragma unroll
  for (int nt = 0; nt < 4; ++nt)
    #pragma unroll
    for (int ks = 0; ks < 2; ++ks) {
      const f16x8 bh = wf[(size_t)(((nt * 2 + ks) * 2) + 0) * 64 + lane];
      const f16x8 bl = wf[(size_t)(((nt * 2 + ks) * 2) + 1) * 64 + lane];
      #pragma unroll
      for (int mf = 0; mf < 2; ++mf) {
        ah[mf][nt] = __builtin_amdgcn_mfma_f32_16x16x32_f16(a1[mf][ks], bh, ah[mf][nt], 0, 0, 0);
        al[mf][nt] = __builtin_amdgcn_mfma_f32_16x16x32_f16(a1[mf][ks], bl, al[mf][nt], 0, 0, 0);
      }
    }
  #pragma unroll
  for (int mf = 0; mf < 2; ++mf)
    #pragma unroll
    for (int i = 0; i < 4; ++i) {
      const int row = r0 + mf * 16 + kg * 4 + i;
      const int swz = (row & 7) << 4;
      #pragma unroll
      for (int nt = 0; nt < 4; ++nt) {
        float v = fmaf(al[mf][nt][i], LO_INV, ah[mf][nt][i]);
        v = fmaxf(v, 0.f);
        *(__half*)(sm + H1_OFF + row * 128 + (((nt * 16 + nl) * 2) ^ swz)) = __float2half(v);
      }
    }

  // -------- L2: K=64, N=32 --------
  f16x8 a2[2][2];
  #pragma unroll
  for (int mf = 0; mf < 2; ++mf) {
    const int row = r0 + mf * 16 + nl;
    const int swz = (row & 7) << 4;
    #pragma unroll
    for (int ks = 0; ks < 2; ++ks)
      a2[mf][ks] = *(const f16x8*)(sm + H1_OFF + row * 128 + ((ks * 64 + kg * 16) ^ swz));
  }
  f32x4 ch[2][2], cl[2][2];
  #pragma unroll
  for (int nt = 0; nt < 2; ++nt) {
    const float bb = b2m[nt * 16 + nl];
    #pragma unroll
    for (int mf = 0; mf < 2; ++mf) {
      ch[mf][nt] = f32x4{bb, bb, bb, bb};
      cl[mf][nt] = f32x4{0.f, 0.f, 0.f, 0.f};
    }
  }
  #pragma unroll
  for (int nt = 0; nt < 2; ++nt)
    #pragma unroll
    for (int ks = 0; ks < 2; ++ks) {
      const f16x8 bh = wf[(size_t)(16 + ((nt * 2 + ks) * 2) + 0) * 64 + lane];
      const f16x8 bl = wf[(size_t)(16 + ((nt * 2 + ks) * 2) + 1) * 64 + lane];
      #pragma unroll
      for (int mf = 0; mf < 2; ++mf) {
        ch[mf][nt] = __builtin_amdgcn_mfma_f32_16x16x32_f16(a2[mf][ks], bh, ch[mf][nt], 0, 0, 0);
        cl[mf][nt] = __builtin_amdgcn_mfma_f32_16x16x32_f16(a2[mf][ks], bl, cl[mf][nt], 0, 0, 0);
      }
    }
  #pragma unroll
  for (int mf = 0; mf < 2; ++mf)
    #pragma unroll
    for (int i = 0; i < 4; ++i) {
      const int row = r0 + mf * 16 + kg * 4 + i;
      const int swz = (row & 3) << 4;
      #pragma unroll
      for (int nt = 0; nt < 2; ++nt) {
        float v = fmaf(cl[mf][nt][i], LO_INV, ch[mf][nt][i]);
        v = fmaxf(v, 0.f);
        *(__half*)(sm + H2_OFF + row * 64 + (((nt * 16 + nl) * 2) ^ swz)) = __float2half(v);
      }
    }

  // -------- L3: K=32, N=64 --------
  f16x8 a3[2];
  #pragma unroll
  for (int mf = 0; mf < 2; ++mf) {
    const int row = r0 + mf * 16 + nl;
    a3[mf] = *(const f16x8*)(sm + H2_OFF + row * 64 + ((kg * 16) ^ ((row & 3) << 4)));
  }
  #pragma unroll
  for (int nt = 0; nt < 4; ++nt) {
    const float bb = b3m[nt * 16 + nl];
    #pragma unroll
    for (int mf = 0; mf < 2; ++mf) {
      oh[mf][nt] = f32x4{bb, bb, bb, bb};
      ol[mf][nt] = f32x4{0.f, 0.f, 0.f, 0.f};
    }
  }
  #pragma unroll
  for (int nt = 0; nt < 4; ++nt) {
    const f16x8 bh = wf[(size_t)(24 + nt * 2 + 0) * 64 + lane];
    const f16x8 bl = wf[(size_t)(24 + nt * 2 + 1) * 64 + lane];
    #pragma unroll
    for (int mf = 0; mf < 2; ++mf) {
      oh[mf][nt] = __builtin_amdgcn_mfma_f32_16x16x32_f16(a3[mf], bh, oh[mf][nt], 0, 0, 0);
      ol[mf][nt] = __builtin_amdgcn_mfma_f32_16x16x32_f16(a3[mf], bl, ol[mf][nt], 0, 0, 0);
    }
  }
}

// ---------------- one coupling half-step (in-place: scale pass then add pass) ----------------
__device__ __forceinline__ void halfstep(
    char* sm, int r0, int lane, int inByteOff, int outCol0,
    const __half* __restrict__ wp, const float* __restrict__ b1,
    const float* __restrict__ b2, const float* __restrict__ b3,
    int mlpS, int mlpT)
{
  const int nl = lane & 15, kg = lane >> 4;

  // s-pass: h[out] *= exp(1.272*atan(s))
  f32x4 sh[2][4], sl[2][4];
  run_mlp(sm, r0, lane, inByteOff, wp + (size_t)mlpS * 16384,
          b1 + mlpS * 64, b2 + mlpS * 32, b3 + mlpS * 64, sh, sl);
  #pragma unroll
  for (int mf = 0; mf < 2; ++mf)
    #pragma unroll
    for (int i = 0; i < 4; ++i) {
      const int row = r0 + mf * 16 + kg * 4 + i;
      const int swz = (row & 7) << 4;
      #pragma unroll
      for (int nt = 0; nt < 4; ++nt) {
        float v = fmaf(sl[mf][nt][i], LO_INV, sh[mf][nt][i]);
        float m = __expf(1.272f * atan_f(v));
        char* p = sm + H_OFF + row * 256 + ((((outCol0 + nt * 16 + nl)) * 2) ^ swz);
        float xv = __half2float(*(const __half*)p);
        *(__half*)p = __float2half(m * xv);
      }
    }

  // t-pass: h[out] += t
  f32x4 th[2][4], tl[2][4];
  run_mlp(sm, r0, lane, inByteOff, wp + (size_t)mlpT * 16384,
          b1 + mlpT * 64, b2 + mlpT * 32, b3 + mlpT * 64, th, tl);
  #pragma unroll
  for (int mf = 0; mf < 2; ++mf)
    #pragma unroll
    for (int i = 0; i < 4; ++i) {
      const int row = r0 + mf * 16 + kg * 4 + i;
      const int swz = (row & 7) << 4;
      #pragma unroll
      for (int nt = 0; nt < 4; ++nt) {
        float t = fmaf(tl[mf][nt][i], LO_INV, th[mf][nt][i]);
        char* p = sm + H_OFF + row * 256 + ((((outCol0 + nt * 16 + nl)) * 2) ^ swz);
        float y = __half2float(*(const __half*)p) + t;
        *(__half*)p = __float2half(y);
      }
    }
}

// ---------------- main fused kernel ----------------
__global__ __launch_bounds__(THREADS) void fused_flow_mfma(
    const float* __restrict__ x, const float* __restrict__ pad,
    const float* __restrict__ b1, const float* __restrict__ b2,
    const float* __restrict__ b3, const int* __restrict__ perms,
    const __half* __restrict__ wp, float* __restrict__ out)
{
  __shared__ char sm[SMEM_BYTES];
  const int wave = threadIdx.x >> 6, lane = threadIdx.x & 63;
  const int r0 = wave * WAVE_ROWS;
  const size_t gR0 = (size_t)blockIdx.x * WG_ROWS;

  // load h = [x, 0.01*pad] as fp16 into swizzled LDS (wave-private rows; no barriers anywhere)
  #pragma unroll
  for (int it = 0; it < 8; ++it) {
    const int row = r0 + it * 4 + (lane >> 4);
    const int swz = (row & 7) << 4;
    const float4 vx = *(const float4*)(x   + (gR0 + row) * 64 + (lane & 15) * 4);
    const float4 vp = *(const float4*)(pad + (gR0 + row) * 64 + (lane & 15) * 4);
    f16x4 hx, hp;
    hx[0] = (_Float16)vx.x; hx[1] = (_Float16)vx.y; hx[2] = (_Float16)vx.z; hx[3] = (_Float16)vx.w;
    hp[0] = (_Float16)(0.01f * vp.x); hp[1] = (_Float16)(0.01f * vp.y);
    hp[2] = (_Float16)(0.01f * vp.z); hp[3] = (_Float16)(0.01f * vp.w);
    *(f16x4*)(sm + H_OFF + row * 256 + ((      8 * (lane & 15)) ^ swz)) = hx;
    *(f16x4*)(sm + H_OFF + row * 256 + ((128 + 8 * (lane & 15)) ^ swz)) = hp;
  }

  for (int blk = 0; blk < NBLK; ++blk) {
    // half-step 1: input x2 (cols 64..127), update x1 slot -> y1
    halfstep(sm, r0, lane, 128, 0, wp, b1, b2, b3, blk * 4 + 2, blk * 4 + 3);
    // half-step 2: input y1 (cols 0..63), update x2 slot -> y2
    halfstep(sm, r0, lane, 0, 64, wp, b1, b2, b3, blk * 4 + 0, blk * 4 + 1);

    // physical column permutation (within-row shuffle; lockstep wave, LDS FIFO per wave)
    const int2 pp = *(const int2*)(perms + blk * 128 + 2 * lane);
    for (int rr = 0; rr < WAVE_ROWS; ++rr) {
      const int row = r0 + rr;
      const int swz = (row & 7) << 4;
      const unsigned short v0 = *(const unsigned short*)(sm + H_OFF + row * 256 + ((pp.x * 2) ^ swz));
      const unsigned short v1 = *(const unsigned short*)(sm + H_OFF + row * 256 + ((pp.y * 2) ^ swz));
      const unsigned u = ((unsigned)v1 << 16) | v0;
      *(unsigned*)(sm + H_OFF + row * 256 + ((4 * lane) ^ swz)) = u;
    }
  }

  // store out (f32), 2 cols per lane per row
  for (int rr = 0; rr < WAVE_ROWS; ++rr) {
    const int row = r0 + rr;
    const int swz = (row & 7) << 4;
    const unsigned u = *(const unsigned*)(sm + H_OFF + row * 256 + ((4 * lane) ^ swz));
    float2 o;
    o.x = __half2float(__ushort_as_half((unsigned short)(u & 0xffff)));
    o.y = __half2float(__ushort_as_half((unsigned short)(u >> 16)));
    *(float2*)(out + (gR0 + row) * 128 + 2 * lane) = o;
  }
}

extern "C" void kernel_launch(void* const* d_in, const int* in_sizes, int n_in,
                              void* d_out, int out_size, void* d_ws, size_t ws_size,
                              hipStream_t stream) {
  const float* x    = (const float*)d_in[0];
  const float* pad  = (const float*)d_in[1];
  const float* W1   = (const float*)d_in[2];
  const float* b1   = (const float*)d_in[3];
  const float* W2   = (const float*)d_in[4];
  const float* b2   = (const float*)d_in[5];
  const float* W3   = (const float*)d_in[6];
  const float* b3   = (const float*)d_in[7];
  const int*   perms= (const int*)d_in[8];
  float* out = (float*)d_out;
  __half* wp = (__half*)d_ws;   // 20 * 16384 f16 = 640 KB packed weights

  pack_weights<<<80, 256, 0, stream>>>(W1, W2, W3, wp);
  fused_flow_mfma<<<B_ROWS / WG_ROWS, THREADS, 0, stream>>>(
      x, pad, b1, b2, b3, perms, wp, out);
}

// Round 3
// 763.878 us; speedup vs baseline: 7.8792x; 1.1146x over previous
//
#include <hip/hip_runtime.h>
#include <hip/hip_fp16.h>

typedef _Float16 f16x8 __attribute__((ext_vector_type(8)));
typedef _Float16 f16x4 __attribute__((ext_vector_type(4)));
typedef float    f32x4 __attribute__((ext_vector_type(4)));

#define B_ROWS    262144
#define WG_ROWS   128
#define THREADS   256
#define NBLK      5

// LDS: h (128 rows x 256B) + h1 (128 rows x 128B; h2 aliases h1 rows in-place)
#define H_OFF   0
#define H1_OFF  32768
#define SMEM_BYTES 49152

// row swizzle: spreads rows {i,i+4,i+8,i+12} (one b16-store's lanes) across all 32 banks
__device__ __forceinline__ int swzR(int row) { return ((row & 7) << 4) ^ ((row & 8) << 2); }

// ---------------- weight packing: fp16 MFMA B-fragments ----------------
// Per MLP: 16 frags x 64 lanes x 8 f16 (16 KB).  frag idx:
//   L1 (K=64,N=64): frag = nt*2+ks        (nt 0..3, ks 0..1)
//   L2 (K=64,N=32): frag = 8 + nt*2+ks    (nt 0..1)
//   L3 (K=32,N=64): frag = 12 + nt        (nt 0..3)
// B-frag lane map (16x16x32): lane l holds B[k = ks*32 + (l>>4)*8 + j][n = nt*16 + (l&15)]
__global__ __launch_bounds__(256) void pack_weights(
    const float* __restrict__ W1, const float* __restrict__ W2,
    const float* __restrict__ W3, __half* __restrict__ wp)
{
  int idx = blockIdx.x * 256 + threadIdx.x;   // 20 * 16 * 64 = 20480
  if (idx >= 20480) return;
  int mlp  = idx >> 10;
  int rem  = idx & 1023;
  int s    = rem >> 6;          // frag 0..15
  int lane = rem & 63;
  int kg = lane >> 4, nl = lane & 15;

  int k0, n, stride; const float* src;
  if (s < 8) {                  // L1
    k0 = (s & 1) * 32 + kg * 8;
    n  = (s >> 1) * 16 + nl;
    src = W1 + (size_t)mlp * 4096; stride = 64;
  } else if (s < 12) {          // L2
    int s2 = s - 8;
    k0 = (s2 & 1) * 32 + kg * 8;
    n  = (s2 >> 1) * 16 + nl;
    src = W2 + (size_t)mlp * 2048; stride = 32;
  } else {                      // L3
    int s3 = s - 12;
    k0 = kg * 8;
    n  = s3 * 16 + nl;
    src = W3 + (size_t)mlp * 2048; stride = 64;
  }
  __half* d = wp + (size_t)mlp * 8192 + (size_t)s * 512 + lane * 8;
  #pragma unroll
  for (int j = 0; j < 8; ++j)
    d[j] = __float2half(src[(size_t)(k0 + j) * stride + n]);
}

// ---------------- math helpers ----------------
__device__ __forceinline__ float atan_f(float x) {
  float ax  = fabsf(x);
  bool  big = ax > 1.0f;
  float z   = big ? __builtin_amdgcn_rcpf(ax) : ax;
  float s   = z * z;
  float p   = -0.01172120f;
  p = fmaf(p, s,  0.05265332f);
  p = fmaf(p, s, -0.11643287f);
  p = fmaf(p, s,  0.19354346f);
  p = fmaf(p, s, -0.33262347f);
  p = fmaf(p, s,  0.99997726f);
  p = p * z;
  float r = big ? (1.57079632679f - p) : p;
  return (x < 0.0f) ? -r : r;
}

// ---------------- one 3-layer MLP (fp16 weights) on this wave's 32 rows ----------------
// a1: preloaded input A-fragments. Output acc o[mf][nt]: C/D map col=l&15, row=(l>>4)*4+reg.
// h1/h2 both live in the H1 region (h2 reuses each row's bytes after a2 is consumed).
__device__ __forceinline__ void run_mlp(
    char* sm, int r0, int lane, const f16x8 a1[2][2],
    const f16x8* __restrict__ wf,
    const float* __restrict__ b1m, const float* __restrict__ b2m,
    const float* __restrict__ b3m,
    f32x4 o[2][4])
{
  const int nl = lane & 15, kg = lane >> 4;

  // -------- L1: K=64, N=64 --------
  f32x4 ah[2][4];
  #pragma unroll
  for (int nt = 0; nt < 4; ++nt) {
    const float bb = b1m[nt * 16 + nl];
    #pragma unroll
    for (int mf = 0; mf < 2; ++mf) ah[mf][nt] = f32x4{bb, bb, bb, bb};
  }
  #pragma unroll
  for (int nt = 0; nt < 4; ++nt)
    #pragma unroll
    for (int ks = 0; ks < 2; ++ks) {
      const f16x8 b = wf[(size_t)(nt * 2 + ks) * 64 + lane];
      #pragma unroll
      for (int mf = 0; mf < 2; ++mf)
        ah[mf][nt] = __builtin_amdgcn_mfma_f32_16x16x32_f16(a1[mf][ks], b, ah[mf][nt], 0, 0, 0);
    }
  #pragma unroll
  for (int mf = 0; mf < 2; ++mf)
    #pragma unroll
    for (int i = 0; i < 4; ++i) {
      const int row = r0 + mf * 16 + kg * 4 + i;
      const int sz  = swzR(row);
      #pragma unroll
      for (int nt = 0; nt < 4; ++nt) {
        float v = fmaxf(ah[mf][nt][i], 0.f);
        *(__half*)(sm + H1_OFF + row * 128 + (((nt * 16 + nl) * 2) ^ sz)) = __float2half(v);
      }
    }

  // -------- L2: K=64, N=32 --------
  f16x8 a2[2][2];
  #pragma unroll
  for (int mf = 0; mf < 2; ++mf) {
    const int row = r0 + mf * 16 + nl;
    const int sz  = swzR(row);
    #pragma unroll
    for (int ks = 0; ks < 2; ++ks)
      a2[mf][ks] = *(const f16x8*)(sm + H1_OFF + row * 128 + ((ks * 64 + kg * 16) ^ sz));
  }
  f32x4 ch[2][2];
  #pragma unroll
  for (int nt = 0; nt < 2; ++nt) {
    const float bb = b2m[nt * 16 + nl];
    #pragma unroll
    for (int mf = 0; mf < 2; ++mf) ch[mf][nt] = f32x4{bb, bb, bb, bb};
  }
  #pragma unroll
  for (int nt = 0; nt < 2; ++nt)
    #pragma unroll
    for (int ks = 0; ks < 2; ++ks) {
      const f16x8 b = wf[(size_t)(8 + nt * 2 + ks) * 64 + lane];
      #pragma unroll
      for (int mf = 0; mf < 2; ++mf)
        ch[mf][nt] = __builtin_amdgcn_mfma_f32_16x16x32_f16(a2[mf][ks], b, ch[mf][nt], 0, 0, 0);
    }
  // h2 -> same H1 rows (bytes {(c*2)^sz, c<32}; a2 already consumed)
  #pragma unroll
  for (int mf = 0; mf < 2; ++mf)
    #pragma unroll
    for (int i = 0; i < 4; ++i) {
      const int row = r0 + mf * 16 + kg * 4 + i;
      const int sz  = swzR(row);
      #pragma unroll
      for (int nt = 0; nt < 2; ++nt) {
        float v = fmaxf(ch[mf][nt][i], 0.f);
        *(__half*)(sm + H1_OFF + row * 128 + (((nt * 16 + nl) * 2) ^ sz)) = __float2half(v);
      }
    }

  // -------- L3: K=32, N=64 --------
  f16x8 a3[2];
  #pragma unroll
  for (int mf = 0; mf < 2; ++mf) {
    const int row = r0 + mf * 16 + nl;
    a3[mf] = *(const f16x8*)(sm + H1_OFF + row * 128 + ((kg * 16) ^ swzR(row)));
  }
  #pragma unroll
  for (int nt = 0; nt < 4; ++nt) {
    const float bb = b3m[nt * 16 + nl];
    #pragma unroll
    for (int mf = 0; mf < 2; ++mf) o[mf][nt] = f32x4{bb, bb, bb, bb};
  }
  #pragma unroll
  for (int nt = 0; nt < 4; ++nt) {
    const f16x8 b = wf[(size_t)(12 + nt) * 64 + lane];
    #pragma unroll
    for (int mf = 0; mf < 2; ++mf)
      o[mf][nt] = __builtin_amdgcn_mfma_f32_16x16x32_f16(a3[mf], b, o[mf][nt], 0, 0, 0);
  }
}

// ---------------- one coupling half-step, s & t fused ----------------
__device__ __forceinline__ void halfstep(
    char* sm, int r0, int lane, int inByteOff, int outCol0,
    const __half* __restrict__ wp, const float* __restrict__ b1,
    const float* __restrict__ b2, const float* __restrict__ b3,
    int mlpS, int mlpT)
{
  const int nl = lane & 15, kg = lane >> 4;

  // shared input A-fragments for both MLPs
  f16x8 a1[2][2];
  #pragma unroll
  for (int mf = 0; mf < 2; ++mf) {
    const int row = r0 + mf * 16 + nl;
    const int sz  = swzR(row);
    #pragma unroll
    for (int ks = 0; ks < 2; ++ks)
      a1[mf][ks] = *(const f16x8*)(sm + H_OFF + row * 256 + ((inByteOff + ks * 64 + kg * 16) ^ sz));
  }

  // s-MLP, then convert to multipliers (VALU overlaps t's MFMAs)
  f32x4 sacc[2][4];
  run_mlp(sm, r0, lane, a1, (const f16x8*)wp + (size_t)mlpS * 1024,
          b1 + mlpS * 64, b2 + mlpS * 32, b3 + mlpS * 64, sacc);
  float m[2][4][4];
  #pragma unroll
  for (int mf = 0; mf < 2; ++mf)
    #pragma unroll
    for (int nt = 0; nt < 4; ++nt)
      #pragma unroll
      for (int i = 0; i < 4; ++i)
        m[mf][nt][i] = __expf(1.272f * atan_f(sacc[mf][nt][i]));

  // t-MLP (reuses a1; H1 region reuse is safe: s's a2/a3 already consumed)
  f32x4 tacc[2][4];
  run_mlp(sm, r0, lane, a1, (const f16x8*)wp + (size_t)mlpT * 1024,
          b1 + mlpT * 64, b2 + mlpT * 32, b3 + mlpT * 64, tacc);

  // fused epilogue: y = m*x + t  (single LDS read-modify-write)
  #pragma unroll
  for (int mf = 0; mf < 2; ++mf)
    #pragma unroll
    for (int i = 0; i < 4; ++i) {
      const int row = r0 + mf * 16 + kg * 4 + i;
      const int sz  = swzR(row);
      #pragma unroll
      for (int nt = 0; nt < 4; ++nt) {
        char* p = sm + H_OFF + row * 256 + ((((outCol0 + nt * 16 + nl)) * 2) ^ sz);
        float x = __half2float(*(const __half*)p);
        *(__half*)p = __float2half(fmaf(m[mf][nt][i], x, tacc[mf][nt][i]));
      }
    }
}

// ---------------- main fused kernel ----------------
__global__ __launch_bounds__(THREADS, 3) void fused_flow_mfma(
    const float* __restrict__ x, const float* __restrict__ pad,
    const float* __restrict__ b1, const float* __restrict__ b2,
    const float* __restrict__ b3, const int* __restrict__ perms,
    const __half* __restrict__ wp, float* __restrict__ out)
{
  __shared__ char sm[SMEM_BYTES];
  const int wave = threadIdx.x >> 6, lane = threadIdx.x & 63;
  const int r0 = wave * 32;
  const size_t gR0 = (size_t)blockIdx.x * WG_ROWS;

  // load h = [x, 0.01*pad] as fp16 into swizzled LDS (wave-private rows; no barriers anywhere)
  #pragma unroll
  for (int it = 0; it < 8; ++it) {
    const int row = r0 + it * 4 + (lane >> 4);
    const int sz  = swzR(row);
    const float4 vx = *(const float4*)(x   + (gR0 + row) * 64 + (lane & 15) * 4);
    const float4 vp = *(const float4*)(pad + (gR0 + row) * 64 + (lane & 15) * 4);
    f16x4 hx, hp;
    hx[0] = (_Float16)vx.x; hx[1] = (_Float16)vx.y; hx[2] = (_Float16)vx.z; hx[3] = (_Float16)vx.w;
    hp[0] = (_Float16)(0.01f * vp.x); hp[1] = (_Float16)(0.01f * vp.y);
    hp[2] = (_Float16)(0.01f * vp.z); hp[3] = (_Float16)(0.01f * vp.w);
    *(f16x4*)(sm + H_OFF + row * 256 + ((      8 * (lane & 15)) ^ sz)) = hx;
    *(f16x4*)(sm + H_OFF + row * 256 + ((128 + 8 * (lane & 15)) ^ sz)) = hp;
  }

  for (int blk = 0; blk < NBLK; ++blk) {
    // half-step 1: input x2 (cols 64..127), update x1 slot -> y1
    halfstep(sm, r0, lane, 128, 0, wp, b1, b2, b3, blk * 4 + 2, blk * 4 + 3);
    // half-step 2: input y1 (cols 0..63), update x2 slot -> y2
    halfstep(sm, r0, lane, 0, 64, wp, b1, b2, b3, blk * 4 + 0, blk * 4 + 1);

    // physical column permutation (intra-wave lockstep; reads complete before the write issues)
    const int2 pp = *(const int2*)(perms + blk * 128 + 2 * lane);
    for (int rr = 0; rr < 32; ++rr) {
      const int row = r0 + rr;
      const int sz  = swzR(row);
      const unsigned short v0 = *(const unsigned short*)(sm + H_OFF + row * 256 + ((pp.x * 2) ^ sz));
      const unsigned short v1 = *(const unsigned short*)(sm + H_OFF + row * 256 + ((pp.y * 2) ^ sz));
      const unsigned u = ((unsigned)v1 << 16) | v0;
      *(unsigned*)(sm + H_OFF + row * 256 + ((4 * lane) ^ sz)) = u;
    }
  }

  // store out (f32), 2 cols per lane per row
  for (int rr = 0; rr < 32; ++rr) {
    const int row = r0 + rr;
    const int sz  = swzR(row);
    const unsigned u = *(const unsigned*)(sm + H_OFF + row * 256 + ((4 * lane) ^ sz));
    float2 o;
    o.x = __half2float(__ushort_as_half((unsigned short)(u & 0xffff)));
    o.y = __half2float(__ushort_as_half((unsigned short)(u >> 16)));
    *(float2*)(out + (gR0 + row) * 128 + 2 * lane) = o;
  }
}

extern "C" void kernel_launch(void* const* d_in, const int* in_sizes, int n_in,
                              void* d_out, int out_size, void* d_ws, size_t ws_size,
                              hipStream_t stream) {
  const float* x    = (const float*)d_in[0];
  const float* pad  = (const float*)d_in[1];
  const float* W1   = (const float*)d_in[2];
  const float* b1   = (const float*)d_in[3];
  const float* W2   = (const float*)d_in[4];
  const float* b2   = (const float*)d_in[5];
  const float* W3   = (const float*)d_in[6];
  const float* b3   = (const float*)d_in[7];
  const int*   perms= (const int*)d_in[8];
  float* out = (float*)d_out;
  __half* wp = (__half*)d_ws;   // 20 * 8192 f16 = 320 KB packed weights

  pack_weights<<<80, 256, 0, stream>>>(W1, W2, W3, wp);
  fused_flow_mfma<<<B_ROWS / WG_ROWS, THREADS, 0, stream>>>(
      x, pad, b1, b2, b3, perms, wp, out);
}

// Round 5
// 604.219 us; speedup vs baseline: 9.9612x; 1.2642x over previous
//
#include <hip/hip_runtime.h>
#include <hip/hip_fp16.h>

typedef _Float16 f16x8 __attribute__((ext_vector_type(8)));
typedef _Float16 f16x4 __attribute__((ext_vector_type(4)));
typedef float    f32x4 __attribute__((ext_vector_type(4)));

#define B_ROWS    262144
#define WG_ROWS   128
#define THREADS   256
#define NBLK      5

// LDS: h (128 rows x 256B) + h1 (128 rows x 128B; h2 aliases h1 rows bytes 0..63)
#define H_OFF   0
#define H1_OFF  32768
#define SMEM_BYTES 49152

// row swizzles (16B-granular XOR, keeps 8B alignment of b64 ops)
__device__ __forceinline__ int swzR(int row) { return ((row & 7) << 4) ^ ((row & 8) << 2); }  // for 128/256B rows
__device__ __forceinline__ int swz2(int row) { return ((row & 3) << 4) ^ ((row & 4) << 3); }  // for 64B h2 span

// ---------------- weight packing: fp16 MFMA fragments ----------------
// NOTE: identical data layout to round 3 (A-frag and B-frag lane maps coincide);
// the main kernel now feeds these as the A operand (weights^T: m=out_feat, k=in_feat).
//   L1 (K=64,M=64): frag = mt*2+ks        (mt 0..3, ks 0..1)
//   L2 (K=64,M=32): frag = 8 + mt*2+ks    (mt 0..1)
//   L3 (K=32,M=64): frag = 12 + mt        (mt 0..3)
// lane l holds W[k = ks*32 + (l>>4)*8 + j][m = mt*16 + (l&15)]
__global__ __launch_bounds__(256) void pack_weights(
    const float* __restrict__ W1, const float* __restrict__ W2,
    const float* __restrict__ W3, __half* __restrict__ wp)
{
  int idx = blockIdx.x * 256 + threadIdx.x;   // 20 * 16 * 64 = 20480
  if (idx >= 20480) return;
  int mlp  = idx >> 10;
  int rem  = idx & 1023;
  int s    = rem >> 6;          // frag 0..15
  int lane = rem & 63;
  int kg = lane >> 4, nl = lane & 15;

  int k0, n, stride; const float* src;
  if (s < 8) {                  // L1
    k0 = (s & 1) * 32 + kg * 8;
    n  = (s >> 1) * 16 + nl;
    src = W1 + (size_t)mlp * 4096; stride = 64;
  } else if (s < 12) {          // L2
    int s2 = s - 8;
    k0 = (s2 & 1) * 32 + kg * 8;
    n  = (s2 >> 1) * 16 + nl;
    src = W2 + (size_t)mlp * 2048; stride = 32;
  } else {                      // L3
    int s3 = s - 12;
    k0 = kg * 8;
    n  = s3 * 16 + nl;
    src = W3 + (size_t)mlp * 2048; stride = 64;
  }
  __half* d = wp + (size_t)mlp * 8192 + (size_t)s * 512 + lane * 8;
  #pragma unroll
  for (int j = 0; j < 8; ++j)
    d[j] = __float2half(src[(size_t)(k0 + j) * stride + n]);
}

// ---------------- math helpers ----------------
__device__ __forceinline__ float atan_f(float x) {
  float ax  = fabsf(x);
  bool  big = ax > 1.0f;
  float z   = big ? __builtin_amdgcn_rcpf(ax) : ax;
  float s   = z * z;
  float p   = -0.01172120f;
  p = fmaf(p, s,  0.05265332f);
  p = fmaf(p, s, -0.11643287f);
  p = fmaf(p, s,  0.19354346f);
  p = fmaf(p, s, -0.33262347f);
  p = fmaf(p, s,  0.99997726f);
  p = p * z;
  float r = big ? (1.57079632679f - p) : p;
  return (x < 0.0f) ? -r : r;
}

// ---------------- one 3-layer MLP (weights = A operand, activations = B) ----------------
// Output o[mt][nt]: lane holds out-features {mt*16 + (lane>>4)*4 + i} for batch row nt*16+(lane&15).
__device__ __forceinline__ void run_mlp(
    char* sm, int r0, int lane, const f16x8 a1[2][2],
    const f16x8* __restrict__ wf,
    const float* __restrict__ b1m, const float* __restrict__ b2m,
    const float* __restrict__ b3m,
    f32x4 o[4][2])
{
  const int nl = lane & 15, kg = lane >> 4;

  // -------- L1: M=64 feats, N=32 rows, K=64 --------
  f32x4 acc1[4][2];
  #pragma unroll
  for (int mt = 0; mt < 4; ++mt) {
    const f32x4 bb = *(const f32x4*)(b1m + mt * 16 + kg * 4);
    acc1[mt][0] = bb; acc1[mt][1] = bb;
  }
  #pragma unroll
  for (int mt = 0; mt < 4; ++mt)
    #pragma unroll
    for (int ks = 0; ks < 2; ++ks) {
      const f16x8 w = wf[(size_t)(mt * 2 + ks) * 64 + lane];
      #pragma unroll
      for (int nt = 0; nt < 2; ++nt)
        acc1[mt][nt] = __builtin_amdgcn_mfma_f32_16x16x32_f16(w, a1[nt][ks], acc1[mt][nt], 0, 0, 0);
    }
  // store h1 (relu), 4 consecutive feats -> one b64 per (mt,nt)
  #pragma unroll
  for (int nt = 0; nt < 2; ++nt) {
    const int row = r0 + nt * 16 + nl;
    const int sz  = swzR(row);
    #pragma unroll
    for (int mt = 0; mt < 4; ++mt) {
      f16x4 v;
      #pragma unroll
      for (int i = 0; i < 4; ++i) v[i] = (_Float16)fmaxf(acc1[mt][nt][i], 0.f);
      *(f16x4*)(sm + H1_OFF + row * 128 + ((mt * 32 + kg * 8) ^ sz)) = v;
    }
  }

  // -------- L2: M=32, N=32, K=64 --------
  f16x8 a2[2][2];
  #pragma unroll
  for (int nt = 0; nt < 2; ++nt) {
    const int row = r0 + nt * 16 + nl;
    const int sz  = swzR(row);
    #pragma unroll
    for (int ks = 0; ks < 2; ++ks)
      a2[nt][ks] = *(const f16x8*)(sm + H1_OFF + row * 128 + ((ks * 64 + kg * 16) ^ sz));
  }
  f32x4 acc2[2][2];
  #pragma unroll
  for (int mt = 0; mt < 2; ++mt) {
    const f32x4 bb = *(const f32x4*)(b2m + mt * 16 + kg * 4);
    acc2[mt][0] = bb; acc2[mt][1] = bb;
  }
  #pragma unroll
  for (int mt = 0; mt < 2; ++mt)
    #pragma unroll
    for (int ks = 0; ks < 2; ++ks) {
      const f16x8 w = wf[(size_t)(8 + mt * 2 + ks) * 64 + lane];
      #pragma unroll
      for (int nt = 0; nt < 2; ++nt)
        acc2[mt][nt] = __builtin_amdgcn_mfma_f32_16x16x32_f16(w, a2[nt][ks], acc2[mt][nt], 0, 0, 0);
    }
  // store h2 into h1 rows, bytes 0..63 (a2 already consumed; 64B-span swizzle)
  #pragma unroll
  for (int nt = 0; nt < 2; ++nt) {
    const int row = r0 + nt * 16 + nl;
    const int sz  = swz2(row);
    #pragma unroll
    for (int mt = 0; mt < 2; ++mt) {
      f16x4 v;
      #pragma unroll
      for (int i = 0; i < 4; ++i) v[i] = (_Float16)fmaxf(acc2[mt][nt][i], 0.f);
      *(f16x4*)(sm + H1_OFF + row * 128 + ((mt * 32 + kg * 8) ^ sz)) = v;
    }
  }

  // -------- L3: M=64, N=32, K=32 --------
  f16x8 a3[2];
  #pragma unroll
  for (int nt = 0; nt < 2; ++nt) {
    const int row = r0 + nt * 16 + nl;
    a3[nt] = *(const f16x8*)(sm + H1_OFF + row * 128 + ((kg * 16) ^ swz2(row)));
  }
  #pragma unroll
  for (int mt = 0; mt < 4; ++mt) {
    const f32x4 bb = *(const f32x4*)(b3m + mt * 16 + kg * 4);
    o[mt][0] = bb; o[mt][1] = bb;
  }
  #pragma unroll
  for (int mt = 0; mt < 4; ++mt) {
    const f16x8 w = wf[(size_t)(12 + mt) * 64 + lane];
    #pragma unroll
    for (int nt = 0; nt < 2; ++nt)
      o[mt][nt] = __builtin_amdgcn_mfma_f32_16x16x32_f16(w, a3[nt], o[mt][nt], 0, 0, 0);
  }
}

// ---------------- one coupling half-step (two-pass epilogue: no m[] live across t-MLP) ----------------
__device__ __forceinline__ void halfstep(
    char* sm, int r0, int lane, int inByteOff, int outByteOff,
    const __half* __restrict__ wp, const float* __restrict__ b1,
    const float* __restrict__ b2, const float* __restrict__ b3,
    int mlpS, int mlpT)
{
  const int nl = lane & 15, kg = lane >> 4;

  // shared input B-fragments for both MLPs
  f16x8 a1[2][2];
  #pragma unroll
  for (int nt = 0; nt < 2; ++nt) {
    const int row = r0 + nt * 16 + nl;
    const int sz  = swzR(row);
    #pragma unroll
    for (int ks = 0; ks < 2; ++ks)
      a1[nt][ks] = *(const f16x8*)(sm + H_OFF + row * 256 + ((inByteOff + ks * 64 + kg * 16) ^ sz));
  }

  // s-MLP, apply multiplier immediately (pass 1): h[out] *= exp(1.272*atan(s))
  f32x4 sacc[4][2];
  run_mlp(sm, r0, lane, a1, (const f16x8*)wp + (size_t)mlpS * 1024,
          b1 + mlpS * 64, b2 + mlpS * 32, b3 + mlpS * 64, sacc);
  #pragma unroll
  for (int nt = 0; nt < 2; ++nt) {
    const int row = r0 + nt * 16 + nl;
    const int sz  = swzR(row);
    #pragma unroll
    for (int mt = 0; mt < 4; ++mt) {
      char* p = sm + H_OFF + row * 256 + ((outByteOff + mt * 32 + kg * 8) ^ sz);
      f16x4 xv = *(const f16x4*)p;
      f16x4 yv;
      #pragma unroll
      for (int i = 0; i < 4; ++i) {
        float m = __expf(1.272f * atan_f(sacc[mt][nt][i]));
        yv[i] = (_Float16)(m * (float)xv[i]);
      }
      *(f16x4*)p = yv;
    }
  }

  // t-MLP (reuses a1; h1/h2 region reuse safe by per-wave program order)
  f32x4 tacc[4][2];
  run_mlp(sm, r0, lane, a1, (const f16x8*)wp + (size_t)mlpT * 1024,
          b1 + mlpT * 64, b2 + mlpT * 32, b3 + mlpT * 64, tacc);
  // pass 2: h[out] += t
  #pragma unroll
  for (int nt = 0; nt < 2; ++nt) {
    const int row = r0 + nt * 16 + nl;
    const int sz  = swzR(row);
    #pragma unroll
    for (int mt = 0; mt < 4; ++mt) {
      char* p = sm + H_OFF + row * 256 + ((outByteOff + mt * 32 + kg * 8) ^ sz);
      f16x4 xv = *(const f16x4*)p;
      f16x4 yv;
      #pragma unroll
      for (int i = 0; i < 4; ++i)
        yv[i] = (_Float16)((float)xv[i] + tacc[mt][nt][i]);
      *(f16x4*)p = yv;
    }
  }
}

// ---------------- main fused kernel ----------------
__global__ __launch_bounds__(THREADS) void fused_flow_mfma(
    const float* __restrict__ x, const float* __restrict__ pad,
    const float* __restrict__ b1, const float* __restrict__ b2,
    const float* __restrict__ b3, const int* __restrict__ perms,
    const __half* __restrict__ wp, float* __restrict__ out)
{
  __shared__ char sm[SMEM_BYTES];
  const int wave = threadIdx.x >> 6, lane = threadIdx.x & 63;
  const int r0 = wave * 32;
  const size_t gR0 = (size_t)blockIdx.x * WG_ROWS;

  // load h = [x, 0.01*pad] as fp16 into swizzled LDS (wave-private rows; no barriers anywhere)
  #pragma unroll
  for (int it = 0; it < 8; ++it) {
    const int row = r0 + it * 4 + (lane >> 4);
    const int sz  = swzR(row);
    const float4 vx = *(const float4*)(x   + (gR0 + row) * 64 + (lane & 15) * 4);
    const float4 vp = *(const float4*)(pad + (gR0 + row) * 64 + (lane & 15) * 4);
    f16x4 hx, hp;
    hx[0] = (_Float16)vx.x; hx[1] = (_Float16)vx.y; hx[2] = (_Float16)vx.z; hx[3] = (_Float16)vx.w;
    hp[0] = (_Float16)(0.01f * vp.x); hp[1] = (_Float16)(0.01f * vp.y);
    hp[2] = (_Float16)(0.01f * vp.z); hp[3] = (_Float16)(0.01f * vp.w);
    *(f16x4*)(sm + H_OFF + row * 256 + ((      8 * (lane & 15)) ^ sz)) = hx;
    *(f16x4*)(sm + H_OFF + row * 256 + ((128 + 8 * (lane & 15)) ^ sz)) = hp;
  }

  for (int blk = 0; blk < NBLK; ++blk) {
    // half-step 1: input x2 (bytes 128..255), update x1 slot (bytes 0..127) -> y1
    halfstep(sm, r0, lane, 128, 0, wp, b1, b2, b3, blk * 4 + 2, blk * 4 + 3);
    // half-step 2: input y1 (bytes 0..127), update x2 slot (bytes 128..255) -> y2
    halfstep(sm, r0, lane, 0, 128, wp, b1, b2, b3, blk * 4 + 0, blk * 4 + 1);

    // physical column permutation (intra-wave lockstep; each lane owns 2 destination cols)
    const int2 pp = *(const int2*)(perms + blk * 128 + 2 * lane);
    for (int rr = 0; rr < 32; ++rr) {
      const int row = r0 + rr;
      const int sz  = swzR(row);
      const unsigned short v0 = *(const unsigned short*)(sm + H_OFF + row * 256 + ((pp.x * 2) ^ sz));
      const unsigned short v1 = *(const unsigned short*)(sm + H_OFF + row * 256 + ((pp.y * 2) ^ sz));
      const unsigned u = ((unsigned)v1 << 16) | v0;
      *(unsigned*)(sm + H_OFF + row * 256 + ((4 * lane) ^ sz)) = u;
    }
  }

  // store out (f32): lane covers 4 consecutive cols of one row; 2 rows per iteration
  for (int rr = 0; rr < 16; ++rr) {
    const int row  = r0 + rr * 2 + (lane >> 5);
    const int sz   = swzR(row);
    const int col4 = (lane & 31) * 4;
    const f16x4 v = *(const f16x4*)(sm + H_OFF + row * 256 + ((col4 * 2) ^ sz));
    float4 o4;
    o4.x = (float)v[0]; o4.y = (float)v[1]; o4.z = (float)v[2]; o4.w = (float)v[3];
    *(float4*)(out + (gR0 + row) * 128 + col4) = o4;
  }
}

extern "C" void kernel_launch(void* const* d_in, const int* in_sizes, int n_in,
                              void* d_out, int out_size, void* d_ws, size_t ws_size,
                              hipStream_t stream) {
  const float* x    = (const float*)d_in[0];
  const float* pad  = (const float*)d_in[1];
  const float* W1   = (const float*)d_in[2];
  const float* b1   = (const float*)d_in[3];
  const float* W2   = (const float*)d_in[4];
  const float* b2   = (const float*)d_in[5];
  const float* W3   = (const float*)d_in[6];
  const float* b3   = (const float*)d_in[7];
  const int*   perms= (const int*)d_in[8];
  float* out = (float*)d_out;
  __half* wp = (__half*)d_ws;   // 20 * 8192 f16 = 320 KB packed weights

  pack_weights<<<80, 256, 0, stream>>>(W1, W2, W3, wp);
  fused_flow_mfma<<<B_ROWS / WG_ROWS, THREADS, 0, stream>>>(
      x, pad, b1, b2, b3, perms, wp, out);
}